// Round 2
// baseline (212.493 us; speedup 1.0000x reference)
//
#include <hip/hip_runtime.h>
#include <math.h>

#define N 512
#define MAX_ITERS 1024
#define NBLOCKS 64
#define TPB 512                 // 8 waves/block
#define WAVES (TPB / 64)        // 8 rows (and 8 cols) per block
#define K (N / 64)              // 8 matrix elements per lane per row
#define CHECK_MASK 7            // convergence check every 8 iterations
#define REL_TOL 1e-6f

// d_ws layout (bytes):
//   0    : unsigned count        (barrier arrival counter)
//   4    : unsigned gen          (barrier generation)
//   8    : unsigned notconv[128] (per-epoch not-converged votes)
//   1024 : float C[512]
//   3072 : float R[512]
#define OFF_NOTCONV 8
#define OFF_C 1024
#define OFF_R 3072

__device__ __forceinline__ float agent_load_f(const float* p) {
    return __hip_atomic_load(p, __ATOMIC_RELAXED, __HIP_MEMORY_SCOPE_AGENT);
}
__device__ __forceinline__ void agent_store_f(float* p, float v) {
    __hip_atomic_store(p, v, __ATOMIC_RELAXED, __HIP_MEMORY_SCOPE_AGENT);
}

// Sense-free monotonic-generation grid barrier. Caller passes strictly
// increasing `expect` (1, 2, 3, ...). Safe because: the releaser resets
// `count` (relaxed) BEFORE the release-store of `gen`, and every other block
// only resumes (and can only re-increment `count`) after acquiring the new
// `gen` (acquire spin-load — the load that observes the release-store carries
// the ordering). All 64 blocks are co-resident (512 waves << 8192 device
// capacity), so no deadlock.
__device__ __forceinline__ void gbar(unsigned* count, unsigned* gen, unsigned expect) {
    __syncthreads();  // drains this block's vmem (incl. agent atomics) before arrival
    if (threadIdx.x == 0) {
        unsigned arrived = __hip_atomic_fetch_add(count, 1u, __ATOMIC_ACQ_REL,
                                                  __HIP_MEMORY_SCOPE_AGENT);
        if (arrived == NBLOCKS - 1) {
            __hip_atomic_store(count, 0u, __ATOMIC_RELAXED, __HIP_MEMORY_SCOPE_AGENT);
            __hip_atomic_store(gen, expect, __ATOMIC_RELEASE, __HIP_MEMORY_SCOPE_AGENT);
        } else {
            while (__hip_atomic_load(gen, __ATOMIC_ACQUIRE, __HIP_MEMORY_SCOPE_AGENT) < expect) {}
        }
    }
    __syncthreads();
}

__global__ void sinkhorn_init(unsigned char* ws) {
    int t = threadIdx.x;  // 512 threads, 1 block
    if (t < 2) ((unsigned*)ws)[t] = 0u;                      // count, gen
    unsigned* notconv = (unsigned*)(ws + OFF_NOTCONV);
    if (t < 128) notconv[t] = 0u;
    float* C = (float*)(ws + OFF_C);
    C[t] = 1.0f;
    // R needs no init: phase A writes every entry before any read.
}

__global__ __launch_bounds__(TPB, 2)
void sinkhorn_persistent(const float* __restrict__ W, float* __restrict__ out,
                         unsigned char* ws) {
    unsigned* count   = (unsigned*)ws;
    unsigned* gen     = (unsigned*)(ws + 4);
    unsigned* notconv = (unsigned*)(ws + OFF_NOTCONV);
    float* C = (float*)(ws + OFF_C);
    float* R = (float*)(ws + OFF_R);

    __shared__ float vec[N];
    __shared__ unsigned sflag;

    const int tid  = threadIdx.x;
    const int b    = blockIdx.x;
    const int wave = tid >> 6;
    const int lane = tid & 63;
    const int row  = b * WAVES + wave;   // this wave's row (phase A) and col (phase B)

    // One-time load: |W0| row fragment (coalesced) and |W0|^T col fragment
    // (strided; one-time cost through L2/L3).
    float wr[K], wt[K];
#pragma unroll
    for (int k = 0; k < K; ++k) {
        wr[k] = fabsf(W[row * N + lane + 64 * k]);
        wt[k] = fabsf(W[(lane + 64 * k) * N + row]);
    }

    float rlocal = 0.0f;   // lane 0: R[row]
    float cprev  = 1.0f;   // lane 0: C[row] at last convergence check
    unsigned bar = 1;

    for (int iter = 0; iter < MAX_ITERS; ++iter) {
        // ---------- phase A: R = 1 / (|W0| @ C) ----------
        vec[tid] = agent_load_f(&C[tid]);
        __syncthreads();
        float s = 0.0f;
#pragma unroll
        for (int k = 0; k < K; ++k) s += wr[k] * vec[lane + 64 * k];
#pragma unroll
        for (int off = 32; off > 0; off >>= 1) s += __shfl_xor(s, off, 64);
        if (lane == 0) {
            rlocal = 1.0f / s;
            agent_store_f(&R[row], rlocal);
        }
        gbar(count, gen, bar++);

        // ---------- phase B: C = 1 / (|W0|^T @ R) ----------
        vec[tid] = agent_load_f(&R[tid]);
        __syncthreads();
        float t = 0.0f;
#pragma unroll
        for (int k = 0; k < K; ++k) t += wt[k] * vec[lane + 64 * k];
#pragma unroll
        for (int off = 32; off > 0; off >>= 1) t += __shfl_xor(t, off, 64);
        const bool check = ((iter & CHECK_MASK) == CHECK_MASK);
        if (lane == 0) {
            float clocal = 1.0f / t;
            agent_store_f(&C[row], clocal);
            if (check) {
                if (fabsf(clocal - cprev) > REL_TOL * cprev) {
                    __hip_atomic_fetch_add(&notconv[iter >> 3], 1u, __ATOMIC_RELAXED,
                                           __HIP_MEMORY_SCOPE_AGENT);
                }
                cprev = clocal;
            }
        }
        gbar(count, gen, bar++);

        if (check) {
            if (tid == 0)
                sflag = __hip_atomic_load(&notconv[iter >> 3], __ATOMIC_RELAXED,
                                          __HIP_MEMORY_SCOPE_AGENT);
            __syncthreads();
            if (sflag == 0) break;   // uniform across all blocks (fixed post-barrier)
        }
    }

    // ---------- epilogue: out[i][j] = |W0[i][j]| * R_i * C_j ----------
    // Last gbar (end of phase B) release-orders all final C writes.
    vec[tid] = agent_load_f(&C[tid]);
    __syncthreads();
    float Rr = __shfl(rlocal, 0, 64);
#pragma unroll
    for (int k = 0; k < K; ++k)
        out[row * N + lane + 64 * k] = wr[k] * Rr * vec[lane + 64 * k];
}

extern "C" void kernel_launch(void* const* d_in, const int* in_sizes, int n_in,
                              void* d_out, int out_size, void* d_ws, size_t ws_size,
                              hipStream_t stream) {
    const float* weight = (const float*)d_in[0];
    float* out = (float*)d_out;
    unsigned char* ws = (unsigned char*)d_ws;

    sinkhorn_init<<<1, TPB, 0, stream>>>(ws);
    sinkhorn_persistent<<<NBLOCKS, TPB, 0, stream>>>(weight, out, ws);
}

// Round 3
// 123.743 us; speedup vs baseline: 1.7172x; 1.7172x over previous
//
#include <hip/hip_runtime.h>
#include <math.h>

#define N 512
#define MAX_ITERS 1024
#define NBLOCKS 16
#define TPB 1024
#define NWAVES 16              // waves per block
#define RPW 2                  // rows per wave (NBLOCKS*NWAVES*RPW == N)
#define KF 8                   // matrix elements per lane per row (N/64)
#define REL_TOL 1e-6f

// ws: [0]=barrier count, [1]=barrier gen  (8 bytes only)
// Slice exchange buffers live in d_out: float Part[2][NBLOCKS][N] = 64 KB,
// fully overwritten by the epilogue (block 0 alone rewrites bytes [0,64K)).

__device__ __forceinline__ float agent_load_f(const float* p) {
    return __hip_atomic_load(p, __ATOMIC_RELAXED, __HIP_MEMORY_SCOPE_AGENT);
}
__device__ __forceinline__ void agent_store_f(float* p, float v) {
    __hip_atomic_store(p, v, __ATOMIC_RELAXED, __HIP_MEMORY_SCOPE_AGENT);
}

// Monotonic-generation grid barrier (worked in R1: acq_rel arrival orders prior
// stores, acquire spin-load pairs with the release of gen). 16 co-resident blocks.
__device__ __forceinline__ void gbar(unsigned* count, unsigned* gen, unsigned expect) {
    __syncthreads();
    if (threadIdx.x == 0) {
        unsigned arrived = __hip_atomic_fetch_add(count, 1u, __ATOMIC_ACQ_REL,
                                                  __HIP_MEMORY_SCOPE_AGENT);
        if (arrived == NBLOCKS - 1) {
            __hip_atomic_store(count, 0u, __ATOMIC_RELAXED, __HIP_MEMORY_SCOPE_AGENT);
            __hip_atomic_store(gen, expect, __ATOMIC_RELEASE, __HIP_MEMORY_SCOPE_AGENT);
        } else {
            while (__hip_atomic_load(gen, __ATOMIC_ACQUIRE, __HIP_MEMORY_SCOPE_AGENT) < expect) {}
        }
    }
    __syncthreads();
}

__global__ void sinkhorn_init(unsigned* ws) {
    if (threadIdx.x < 2) ws[threadIdx.x] = 0u;
}

__global__ __launch_bounds__(TPB, 2)
void sinkhorn_persistent(const float* __restrict__ W, float* out, unsigned* ws) {
    unsigned* count = ws;
    unsigned* gen   = ws + 1;
    float* Part = out;                         // [2][NBLOCKS][N]

    __shared__ float vec[N];                   // current C vector
    __shared__ float wpart[NWAVES][N];         // per-wave column partials (32 KB)
    __shared__ unsigned swflag[NWAVES];
    __shared__ unsigned sflag;

    const int tid  = threadIdx.x;
    const int b    = blockIdx.x;
    const int wave = tid >> 6;
    const int lane = tid & 63;
    const int r0   = (b * NWAVES + wave) * RPW;   // this wave's rows r0, r0+1

    // One-time load: row fragments only (coalesced). No transposed load needed —
    // column partials come from the same row-major registers.
    float wr[RPW][KF];
#pragma unroll
    for (int a = 0; a < RPW; ++a)
#pragma unroll
        for (int k = 0; k < KF; ++k)
            wr[a][k] = fabsf(W[(r0 + a) * N + lane + 64 * k]);

    // Per-column state: thread tid (<N) owns column tid. Identical trajectories
    // in every block (same committed Part values, same op order) -> uniform break.
    float c = 1.0f, h1 = 1.0f, h2 = 1.0f, cchk = 1.0f;
    float R0 = 0.0f, R1 = 0.0f;
    unsigned bar = 1;

    for (int iter = 0; iter < MAX_ITERS; ++iter) {
        const int wb = iter & 1;               // slice buffer written this iter

        if (iter > 0) {
            // ---- gather previous iteration's slices: C_j = 1/sum_b Part[b][j] ----
            if (tid < N) {
                float s = 0.0f;
#pragma unroll
                for (int bb = 0; bb < NBLOCKS; ++bb)
                    s += agent_load_f(&Part[(wb ^ 1) * (NBLOCKS * N) + bb * N + tid]);
                c = 1.0f / s;
            }
            // ---- convergence check (every 4 iters, raw sequence, pre-extrap) ----
            if ((iter & 3) == 0 && iter >= 12) {
                bool nc = false;
                if (tid < N) { nc = fabsf(c - cchk) > REL_TOL * fabsf(c); cchk = c; }
                unsigned anyv = (unsigned)__any(nc);
                if (lane == 0) swflag[wave] = anyv;
                __syncthreads();
                if (tid == 0) {
                    unsigned f = 0;
#pragma unroll
                    for (int w = 0; w < NWAVES; ++w) f |= swflag[w];
                    sflag = f;
                }
                __syncthreads();
                if (sflag == 0) break;         // uniform across blocks
            }
            // ---- Aitken delta^2 extrapolation every 16 iters ----
            if ((iter & 15) == 0 && iter >= 16 && tid < N) {
                float d1 = c - h1, d0 = h1 - h2;
                float dd = d1 - d0;
                if (fabsf(dd) > 1e-9f * fabsf(c)) {
                    float cx = c - d1 * d1 / dd;
                    if (cx > 0.25f * c && cx < 4.0f * c) c = cx;   // safeguard
                }
            }
            if (tid < N) { h2 = h1; h1 = c; }
        }

        if (tid < N) vec[tid] = c;
        __syncthreads();

        // ---- row step (local): R_r = 1 / sum_j |W0|[r][j] * C_j ----
        float s0 = 0.0f, s1 = 0.0f;
#pragma unroll
        for (int k = 0; k < KF; ++k) {
            float v = vec[lane + 64 * k];
            s0 += wr[0][k] * v;
            s1 += wr[1][k] * v;
        }
#pragma unroll
        for (int off = 32; off > 0; off >>= 1) {
            s0 += __shfl_xor(s0, off, 64);
            s1 += __shfl_xor(s1, off, 64);
        }
        R0 = 1.0f / s0;                        // all lanes hold the full sum
        R1 = 1.0f / s1;

        // ---- column partials (local): P_j += |W0|[r][j] * R_r over my rows ----
#pragma unroll
        for (int k = 0; k < KF; ++k)
            wpart[wave][lane + 64 * k] = wr[0][k] * R0 + wr[1][k] * R1;
        __syncthreads();
        if (tid < N) {
            float P = 0.0f;
#pragma unroll
            for (int w = 0; w < NWAVES; ++w) P += wpart[w][tid];
            agent_store_f(&Part[wb * (NBLOCKS * N) + b * N + tid], P);
        }

        gbar(count, gen, bar++);               // the ONE barrier per iteration
    }

    // ---- epilogue: out[i][j] = |W0[i][j]| * R_i * C_j ----
    // Barrier first: all blocks finished their Part reads before out is clobbered.
    gbar(count, gen, bar++);
    if (tid < N) vec[tid] = c;
    __syncthreads();
#pragma unroll
    for (int a = 0; a < RPW; ++a) {
        float Ra = (a == 0) ? R0 : R1;
#pragma unroll
        for (int k = 0; k < KF; ++k)
            out[(r0 + a) * N + lane + 64 * k] = wr[a][k] * Ra * vec[lane + 64 * k];
    }
}

extern "C" void kernel_launch(void* const* d_in, const int* in_sizes, int n_in,
                              void* d_out, int out_size, void* d_ws, size_t ws_size,
                              hipStream_t stream) {
    const float* weight = (const float*)d_in[0];
    float* out = (float*)d_out;
    unsigned* ws = (unsigned*)d_ws;

    sinkhorn_init<<<1, 64, 0, stream>>>(ws);
    sinkhorn_persistent<<<NBLOCKS, TPB, 0, stream>>>(weight, out, ws);
}